// Round 16
// baseline (2854.441 us; speedup 1.0000x reference)
//
#include <hip/hip_runtime.h>
#include <cstdint>

// ---------------------------------------------------------------------------
// Frustum-PointNet forward, MI355X.  R16 = R14 (best, 2393us) + fused BN
// stats in gemm_big_k epilogue (MODE 1: Y store + fp64 sum/sq partials) for
// Y4, S1-S4, T2, B2, B3 -> drops 8 stats_k full-tensor HBM re-reads.
// MODE 0 = store only, MODE 2 = no-store + sum/sq/max (conv5, T3, B4).
// Stats stay fp64-exact; logits margins >> 1-ulp scale perturbation.
// ---------------------------------------------------------------------------

constexpr int PP   = 65536;   // B*N
constexpr int PP2  = 16384;   // B*M
constexpr int OUTW = 4158;    // 2*N + 59 + 3

constexpr size_t F_Y1 = 0;
constexpr size_t F_Y2 = (size_t)64 * PP;
constexpr size_t F_Y3 = (size_t)128 * PP;
constexpr size_t F_Y4 = (size_t)192 * PP;
constexpr size_t F_P5S = 0;
constexpr size_t F_P5Q = (size_t)2 * 1024 * 1024;
constexpr size_t F_P5M = (size_t)128 * PP;
static_assert(F_P5Q + 2 * 1024 * 1024 <= F_Y2, "P5 partials exceed Y1 slot");
static_assert(F_P5M + 1024 * 1024 <= (size_t)192 * PP, "P5m exceeds Y3 slot");
constexpr size_t F_S1 = (size_t)320 * PP;
constexpr size_t F_S2 = 0;
constexpr size_t F_S3 = (size_t)320 * PP;
constexpr size_t F_S4 = (size_t)448 * PP;
// transient fused-stat partial bases (doubles), liveness-verified:
constexpr size_t F_PA_C4 = 0;                 // conv4: Y1 slot dead
constexpr size_t F_PA_S1 = (size_t)128 * PP;  // S1: Y3/Y4 dead, P5 consumed
constexpr size_t F_PA_S2 = (size_t)256 * PP;  // S2/S3/S4: [256PP,320PP) free
constexpr size_t F_PA_TB = (size_t)448 * PP;  // t/b: post-logits, S-chain dead
constexpr size_t F_T1 = 0;
constexpr size_t F_T2 = F_T1 + (size_t)128 * PP2;
constexpr size_t F_PT = F_T2 + (size_t)256 * PP2;
constexpr size_t F_B1 = F_PT + (size_t)5 * 256 * 512;
constexpr size_t F_B2 = F_B1 + (size_t)128 * PP2;
constexpr size_t F_B3 = F_B2 + (size_t)128 * PP2;
constexpr size_t F_PB = F_B3 + (size_t)256 * PP2;
static_assert(F_PB + (size_t)5 * 256 * 512 <= (size_t)256 * PP, "t/b overlay overflow");
static_assert((F_PT % 2) == 0 && (F_PB % 2) == 0, "double alignment");

constexpr size_t SB       = (size_t)832 * PP;
constexpr size_t F_MASK   = SB;
constexpr size_t F_MIDX   = F_MASK + PP;
constexpr size_t F_CNT    = F_MIDX + PP;
constexpr size_t F_MEAN   = F_CNT + 32;
constexpr size_t F_GVEC   = F_MEAN + 96;
constexpr size_t F_GVT    = F_GVEC + 32 * 1027;
constexpr size_t F_GVB    = F_GVT + 32 * 515;
constexpr size_t F_GDOT   = F_GVB + 32 * 515;
constexpr size_t F_YT1    = F_GDOT + 512 * 32;
constexpr size_t F_YT2    = F_YT1 + 32 * 256;
constexpr size_t F_YB1    = F_YT2 + 32 * 128;
constexpr size_t F_YB2    = F_YB1 + 32 * 512;
constexpr size_t F_CD     = F_YB2 + 32 * 256;
constexpr size_t F_OBJ    = F_CD + 96;
constexpr size_t F_ST     = F_OBJ + (size_t)3 * PP2;
constexpr size_t F_END    = F_ST + 20 * 2048;
constexpr size_t NEED_BYTES = F_END * 4;           // ~219.7 MB

#define NEG_INF (-3.402823466e38f)

// ---------------------------------------------------------------------------
__global__ __launch_bounds__(256) void conv_pc_k(const float* __restrict__ pc,
                                                 const float* __restrict__ W,
                                                 const float* __restrict__ bias,
                                                 float* __restrict__ Y) {
  int p = blockIdx.x * 256 + threadIdx.x;
  int o = blockIdx.y;
  float4 v = *reinterpret_cast<const float4*>(&pc[(size_t)p * 4]);
  float s = bias[o] + v.x * W[o * 4 + 0] + v.y * W[o * 4 + 1] + v.z * W[o * 4 + 2] +
            v.w * W[o * 4 + 3];
  Y[(size_t)o * PP + p] = s;
}

__global__ __launch_bounds__(256) void conv_k3_k(const float* __restrict__ Xc,
                                                 const float* __restrict__ W,
                                                 const float* __restrict__ bias,
                                                 const float* __restrict__ cd,
                                                 float* __restrict__ Y) {
  int p = blockIdx.x * 256 + threadIdx.x;
  int o = blockIdx.y;
  int b = p >> 9;  // M=512
  float x0 = Xc[p], x1 = Xc[PP2 + p], x2 = Xc[2 * PP2 + p];
  if (cd) { x0 -= cd[b * 3]; x1 -= cd[b * 3 + 1]; x2 -= cd[b * 3 + 2]; }
  Y[(size_t)o * PP2 + p] = bias[o] + x0 * W[o * 3] + x1 * W[o * 3 + 1] + x2 * W[o * 3 + 2];
}

// ---------------------------------------------------------------------------
// 64x64-tile fp32 GEMM (O=64 layers conv2/conv3).
__global__ __launch_bounds__(256) void conv_gemm_k(
    const float* __restrict__ X, int ldx, const float* __restrict__ W, int ldw, int C,
    const float* __restrict__ bias, const float* __restrict__ scale,
    const float* __restrict__ shift, int relu_in, float* __restrict__ Y, int Ptot) {
  __shared__ float Xs[16][64];
  __shared__ float Ws[64][17];
  const int tid = threadIdx.x;
  const int tx = tid & 15, ty = tid >> 4;
  const int o0 = blockIdx.x * 64, p0 = blockIdx.y * 64;
  float acc[4][4] = {};
  for (int c0 = 0; c0 < C; c0 += 16) {
#pragma unroll
    for (int j = 0; j < 4; ++j) {
      int idx = tid + j * 256;
      int k = idx >> 6, n = idx & 63;
      int c = c0 + k;
      float v = X[(size_t)c * ldx + p0 + n];
      if (scale) v = v * scale[c] + shift[c];
      if (relu_in) v = fmaxf(v, 0.f);
      Xs[k][n] = v;
    }
#pragma unroll
    for (int j = 0; j < 4; ++j) {
      int idx = tid + j * 256;
      int o = idx >> 4, k = idx & 15;
      Ws[o][k] = W[(size_t)(o0 + o) * ldw + c0 + k];
    }
    __syncthreads();
#pragma unroll
    for (int k = 0; k < 16; ++k) {
      float bx[4], aw[4];
#pragma unroll
      for (int j = 0; j < 4; ++j) bx[j] = Xs[k][tx * 4 + j];
#pragma unroll
      for (int i = 0; i < 4; ++i) aw[i] = Ws[ty * 4 + i][k];
#pragma unroll
      for (int i = 0; i < 4; ++i)
#pragma unroll
        for (int j = 0; j < 4; ++j) acc[i][j] = fmaf(aw[i], bx[j], acc[i][j]);
    }
    __syncthreads();
  }
#pragma unroll
  for (int i = 0; i < 4; ++i) {
    int o = o0 + ty * 4 + i;
    float badd = bias[o];
#pragma unroll
    for (int j = 0; j < 4; ++j) acc[i][j] += badd;
  }
#pragma unroll
  for (int i = 0; i < 4; ++i) {
    int o = o0 + ty * 4 + i;
    float4 v = make_float4(acc[i][0], acc[i][1], acc[i][2], acc[i][3]);
    *reinterpret_cast<float4*>(&Y[(size_t)o * Ptot + p0 + tx * 4]) = v;
  }
}

// ---------------------------------------------------------------------------
// 128x128-tile fp32 GEMM, 8x8 acc/thread, split-halves fragment map (R14).
// MODE 0: Y store only.  MODE 1: Y store + fp64 sum/sq partials.
// MODE 2: no store; fp64 sum/sq + fp32 max partials (maxpool layers).
template <int MODE>
__global__ __launch_bounds__(256) void gemm_big_k(
    const float* __restrict__ X, int ldx, const float* __restrict__ W, int ldw, int C,
    const float* __restrict__ bias, const float* __restrict__ scale,
    const float* __restrict__ shift, int relu_in, const float* __restrict__ gadd,
    float* __restrict__ Y, int Ptot, double* __restrict__ psum, double* __restrict__ psq,
    float* __restrict__ pmax, int Ototal) {
  __shared__ float Xs[16][128];
  __shared__ float Wt[16][128];
  const int tid = threadIdx.x;
  const int tx = tid & 15, ty = tid >> 4;
  const int o0 = blockIdx.x * 128, p0 = blockIdx.y * 128;
  float acc[8][8] = {};
  for (int c0 = 0; c0 < C; c0 += 16) {
#pragma unroll
    for (int q = 0; q < 2; ++q) {
      int f = tid + q * 256;
      int k = f >> 5, c4 = f & 31;
      int c = c0 + k;
      float4 v = *reinterpret_cast<const float4*>(&X[(size_t)c * ldx + p0 + c4 * 4]);
      if (scale) {
        float sc = scale[c], sh = shift[c];
        v.x = v.x * sc + sh; v.y = v.y * sc + sh;
        v.z = v.z * sc + sh; v.w = v.w * sc + sh;
      }
      if (relu_in) {
        v.x = fmaxf(v.x, 0.f); v.y = fmaxf(v.y, 0.f);
        v.z = fmaxf(v.z, 0.f); v.w = fmaxf(v.w, 0.f);
      }
      *reinterpret_cast<float4*>(&Xs[k][c4 * 4]) = v;
    }
#pragma unroll
    for (int q = 0; q < 8; ++q) {
      int idx = tid + q * 256;
      int k = idx >> 7, o = idx & 127;
      Wt[k][o] = W[(size_t)(o0 + o) * ldw + c0 + k];
    }
    __syncthreads();
#pragma unroll
    for (int k = 0; k < 16; ++k) {
      float bx[8], aw[8];
      *reinterpret_cast<float4*>(&bx[0]) =
          *reinterpret_cast<const float4*>(&Xs[k][tx * 4]);
      *reinterpret_cast<float4*>(&bx[4]) =
          *reinterpret_cast<const float4*>(&Xs[k][64 + tx * 4]);
      *reinterpret_cast<float4*>(&aw[0]) =
          *reinterpret_cast<const float4*>(&Wt[k][ty * 4]);
      *reinterpret_cast<float4*>(&aw[4]) =
          *reinterpret_cast<const float4*>(&Wt[k][64 + ty * 4]);
#pragma unroll
      for (int i = 0; i < 8; ++i)
#pragma unroll
        for (int j = 0; j < 8; ++j) acc[i][j] = fmaf(aw[i], bx[j], acc[i][j]);
    }
    __syncthreads();
  }
#pragma unroll
  for (int i = 0; i < 8; ++i) {
    int ro = (i < 4) ? (ty * 4 + i) : (64 + ty * 4 + (i - 4));
    int o = o0 + ro;
    float badd = bias ? bias[o] : 0.f;
    if (gadd) badd += gadd[o * 32 + (p0 >> 11)];
#pragma unroll
    for (int j = 0; j < 8; ++j) acc[i][j] += badd;
  }
  if constexpr (MODE != 2) {
#pragma unroll
    for (int i = 0; i < 8; ++i) {
      int ro = (i < 4) ? (ty * 4 + i) : (64 + ty * 4 + (i - 4));
      float* row = &Y[(size_t)(o0 + ro) * Ptot + p0];
      *reinterpret_cast<float4*>(row + tx * 4) =
          make_float4(acc[i][0], acc[i][1], acc[i][2], acc[i][3]);
      *reinterpret_cast<float4*>(row + 64 + tx * 4) =
          make_float4(acc[i][4], acc[i][5], acc[i][6], acc[i][7]);
    }
  }
  if constexpr (MODE >= 1) {
    __shared__ double redd[16][128];
#pragma unroll
    for (int i = 0; i < 8; ++i) {
      int ro = (i < 4) ? (ty * 4 + i) : (64 + ty * 4 + (i - 4));
      double s = 0.0;
#pragma unroll
      for (int j = 0; j < 8; ++j) s += (double)acc[i][j];
      redd[tx][ro] = s;
    }
    __syncthreads();
    if (tid < 128) {
      double s = 0.0;
      for (int t = 0; t < 16; ++t) s += redd[t][tid];
      psum[(size_t)blockIdx.y * Ototal + o0 + tid] = s;
    }
    __syncthreads();
#pragma unroll
    for (int i = 0; i < 8; ++i) {
      int ro = (i < 4) ? (ty * 4 + i) : (64 + ty * 4 + (i - 4));
      double s = 0.0;
#pragma unroll
      for (int j = 0; j < 8; ++j) s += (double)acc[i][j] * (double)acc[i][j];
      redd[tx][ro] = s;
    }
    __syncthreads();
    if (tid < 128) {
      double s = 0.0;
      for (int t = 0; t < 16; ++t) s += redd[t][tid];
      psq[(size_t)blockIdx.y * Ototal + o0 + tid] = s;
    }
    if constexpr (MODE == 2) {
      __syncthreads();
#pragma unroll
      for (int i = 0; i < 8; ++i) {
        int ro = (i < 4) ? (ty * 4 + i) : (64 + ty * 4 + (i - 4));
        float mx = acc[i][0];
#pragma unroll
        for (int j = 1; j < 8; ++j) mx = fmaxf(mx, acc[i][j]);
        redd[tx][ro] = (double)mx;
      }
      __syncthreads();
      if (tid < 128) {
        double s = -1.0e300;
        for (int t = 0; t < 16; ++t) s = s > redd[t][tid] ? s : redd[t][tid];
        pmax[(size_t)blockIdx.y * Ototal + o0 + tid] = (float)s;
      }
    }
  }
}

// BN stats over stored (O x Ptot) fp32 activation; fp64 accumulation.
__global__ __launch_bounds__(256) void stats_k(const float* __restrict__ Y, int Ptot,
                                               float* __restrict__ scale,
                                               float* __restrict__ shift) {
  int o = blockIdx.x;
  const float* row = Y + (size_t)o * Ptot;
  double s = 0.0, q = 0.0;
  for (int p = threadIdx.x; p < Ptot; p += 256) {
    double v = (double)row[p];
    s += v;
    q += v * v;
  }
  __shared__ double ss[256], qq[256];
  int tid = threadIdx.x;
  ss[tid] = s; qq[tid] = q;
  __syncthreads();
  for (int off = 128; off; off >>= 1) {
    if (tid < off) { ss[tid] += ss[tid + off]; qq[tid] += qq[tid + off]; }
    __syncthreads();
  }
  if (tid == 0) {
    double m = ss[0] / (double)Ptot;
    double v = qq[0] / (double)Ptot - m * m;
    if (v < 0.0) v = 0.0;
    double sc = 1.0 / sqrt(v + 1e-5);
    scale[o] = (float)sc;
    shift[o] = (float)(-m * sc);
  }
}

__global__ void stats_reduce_k(const double* __restrict__ psum, const double* __restrict__ psq,
                               int ntiles, int O, double invP, float* __restrict__ scale,
                               float* __restrict__ shift) {
  int o = blockIdx.x * blockDim.x + threadIdx.x;
  if (o >= O) return;
  double s = 0.0, q = 0.0;
  for (int t = 0; t < ntiles; ++t) {
    s += psum[(size_t)t * O + o];
    q += psq[(size_t)t * O + o];
  }
  double m = s * invP;
  double v = q * invP - m * m;
  if (v < 0.0) v = 0.0;
  double sc = 1.0 / sqrt(v + 1e-5);
  scale[o] = (float)sc;
  shift[o] = (float)(-m * sc);
}

__global__ void maxpool_g_k(const float* __restrict__ pmax, int tilesPB, int O,
                            const float* __restrict__ scale, const float* __restrict__ shift,
                            int relu, float* __restrict__ out, int ostride, int ooff) {
  int idx = blockIdx.x * blockDim.x + threadIdx.x;
  if (idx >= 32 * O) return;
  int b = idx / O, o = idx - b * O;
  float m = NEG_INF;
  for (int t = b * tilesPB; t < (b + 1) * tilesPB; ++t) m = fmaxf(m, pmax[(size_t)t * O + o]);
  float v = scale[o] * m + shift[o];
  if (relu) v = fmaxf(v, 0.f);
  out[(size_t)b * ostride + ooff + o] = v;
}

__global__ void onehot_k(const float* __restrict__ oh, float* __restrict__ gvec,
                         float* __restrict__ gvt, float* __restrict__ gvb) {
  int i = threadIdx.x;
  if (i >= 96) return;
  int b = i / 3, c = i - b * 3;
  float v = oh[b * 3 + c];
  gvec[b * 1027 + c] = v;
  gvt[b * 515 + c] = v;
  gvb[b * 515 + 512 + c] = v;
}

__global__ void gdot_k(const float* __restrict__ W, const float* __restrict__ gvec,
                       float* __restrict__ gdot) {
  int idx = blockIdx.x * 256 + threadIdx.x;  // 512*32
  int o = idx >> 5, b = idx & 31;
  double s = 0.0;
  const float* wr = W + (size_t)o * 1091;
  const float* gr = gvec + (size_t)b * 1027;
  for (int c = 0; c < 1027; ++c) s += (double)wr[c] * (double)gr[c];
  gdot[o * 32 + b] = (float)s;
}

__global__ __launch_bounds__(256) void logits_k(const float* __restrict__ S4,
                                                const float* __restrict__ W,
                                                const float* __restrict__ bias,
                                                const float* __restrict__ scale,
                                                const float* __restrict__ shift,
                                                float* __restrict__ out,
                                                int* __restrict__ mask) {
  int p = blockIdx.x * 256 + threadIdx.x;
  double l0 = (double)bias[0], l1 = (double)bias[1];
  for (int c = 0; c < 128; ++c) {
    float v = fmaxf(S4[(size_t)c * PP + p] * scale[c] + shift[c], 0.f);
    l0 += (double)v * (double)W[c];
    l1 += (double)v * (double)W[128 + c];
  }
  int b = p >> 11, n = p & 2047;
  out[(size_t)b * OUTW + 2 * n] = (float)l0;
  out[(size_t)b * OUTW + 2 * n + 1] = (float)l1;
  mask[p] = (l0 < l1) ? 1 : 0;
}

__global__ __launch_bounds__(256) void compact_k(const int* __restrict__ mask,
                                                 const float* __restrict__ pc,
                                                 int* __restrict__ midx, int* __restrict__ cnt,
                                                 float* __restrict__ meanv) {
  int b = blockIdx.x, tid = threadIdx.x;
  __shared__ int sc[256];
  __shared__ int base;
  __shared__ double red[256];
  __shared__ double totals[3];
  if (tid == 0) base = 0;
  __syncthreads();
  double sx = 0.0, sy = 0.0, sz = 0.0;
  for (int n0 = 0; n0 < 2048; n0 += 256) {
    int n = n0 + tid;
    int mval = mask[b * 2048 + n];
    sc[tid] = mval;
    __syncthreads();
    for (int off = 1; off < 256; off <<= 1) {
      int v = (tid >= off) ? sc[tid - off] : 0;
      __syncthreads();
      sc[tid] += v;
      __syncthreads();
    }
    int excl = sc[tid] - mval;
    if (mval) {
      midx[b * 2048 + base + excl] = n;
      const float* q = &pc[((size_t)(b * 2048 + n)) * 4];
      sx += (double)q[0]; sy += (double)q[1]; sz += (double)q[2];
    }
    __syncthreads();
    if (tid == 0) base += sc[255];
    __syncthreads();
  }
  red[tid] = sx; __syncthreads();
  for (int off = 128; off; off >>= 1) { if (tid < off) red[tid] += red[tid + off]; __syncthreads(); }
  if (tid == 0) totals[0] = red[0];
  __syncthreads();
  red[tid] = sy; __syncthreads();
  for (int off = 128; off; off >>= 1) { if (tid < off) red[tid] += red[tid + off]; __syncthreads(); }
  if (tid == 0) totals[1] = red[0];
  __syncthreads();
  red[tid] = sz; __syncthreads();
  for (int off = 128; off; off >>= 1) { if (tid < off) red[tid] += red[tid + off]; __syncthreads(); }
  if (tid == 0) {
    totals[2] = red[0];
    int c = base;
    cnt[b] = c;
    double d = (double)(c > 1 ? c : 1);
    meanv[b * 3 + 0] = (float)(totals[0] / d);
    meanv[b * 3 + 1] = (float)(totals[1] / d);
    meanv[b * 3 + 2] = (float)(totals[2] / d);
  }
}

// --------------------------- threefry2x32 ----------------------------------
__device__ __forceinline__ uint32_t rotl32(uint32_t x, int r) {
  return (x << r) | (x >> (32 - r));
}
__device__ inline void threefry2x32(uint32_t k0, uint32_t k1, uint32_t& x0, uint32_t& x1) {
  const uint32_t ks[3] = {k0, k1, k0 ^ k1 ^ 0x1BD11BDAu};
  const int rot[2][4] = {{13, 15, 26, 6}, {17, 29, 16, 24}};
  x0 += ks[0]; x1 += ks[1];
  for (int i = 0; i < 5; ++i) {
    const int* r = rot[i & 1];
    for (int j = 0; j < 4; ++j) {
      x0 += x1; x1 = rotl32(x1, r[j]); x1 ^= x0;
    }
    x0 += ks[(i + 1) % 3];
    x1 += ks[(i + 2) % 3] + (uint32_t)(i + 1);
  }
}

// JAX partitionable threefry (default since 0.4.36): ctr (0,e), bits = w0^w1.
__global__ void sample_k(const float* __restrict__ pc, const int* __restrict__ midx,
                         const int* __restrict__ cnt, const float* __restrict__ meanv,
                         float* __restrict__ obj) {
  int e = blockIdx.x * 256 + threadIdx.x;
  if (e >= 16384) return;
  uint32_t x0 = 0u, x1 = (uint32_t)e;
  threefry2x32(0u, 42u, x0, x1);
  uint32_t bits = x0 ^ x1;
  float u = __uint_as_float((bits >> 9) | 0x3F800000u) - 1.0f;
  int b = e >> 9;
  int m = e & 511;
  int c_ = cnt[b];
  int pos = (int)(u * (float)c_);
  int cap = c_ - 1; if (cap < 0) cap = 0;
  if (pos > cap) pos = cap;
  float vx = 0.f, vy = 0.f, vz = 0.f;
  if (c_ > 0) {
    int n = midx[b * 2048 + pos];
    const float* q = &pc[((size_t)(b * 2048 + n)) * 4];
    vx = q[0] - meanv[b * 3 + 0];
    vy = q[1] - meanv[b * 3 + 1];
    vz = q[2] - meanv[b * 3 + 2];
  }
  int p2 = b * 512 + m;
  obj[p2] = vx;
  obj[PP2 + p2] = vy;
  obj[2 * PP2 + p2] = vz;
}

__global__ void fc_gemm_k(const float* __restrict__ Xf, int ldx, int K,
                          const float* __restrict__ W, const float* __restrict__ bias,
                          const float* __restrict__ scale, const float* __restrict__ shift,
                          int relu, float* __restrict__ Y, int ldy, int yoff, int O) {
  int o = blockIdx.x * blockDim.x + threadIdx.x;
  int b = blockIdx.y;
  if (o >= O) return;
  const float* x = Xf + (size_t)b * ldx;
  const float* w = W + (size_t)o * K;
  double s = bias ? (double)bias[o] : 0.0;
  for (int k = 0; k < K; ++k) {
    float v = x[k];
    if (scale) {
      v = v * scale[k] + shift[k];
      if (relu) v = fmaxf(v, 0.f);
    }
    s += (double)v * (double)w[k];
  }
  Y[(size_t)b * ldy + yoff + o] = (float)s;
}

__global__ void fc_stats_k(const float* __restrict__ Y, int ldy, int O,
                           float* __restrict__ scale, float* __restrict__ shift) {
  int o = blockIdx.x * blockDim.x + threadIdx.x;
  if (o >= O) return;
  double s = 0.0, q = 0.0;
  for (int b = 0; b < 32; ++b) {
    double v = (double)Y[(size_t)b * ldy + o];
    s += v;
    q += v * v;
  }
  double m = s / 32.0;
  double v = q / 32.0 - m * m;
  if (v < 0.0) v = 0.0;
  double sc = 1.0 / sqrt(v + 1e-5);
  scale[o] = (float)sc;
  shift[o] = (float)(-m * sc);
}

__global__ void center_k(float* __restrict__ out, const float* __restrict__ cd,
                         const float* __restrict__ meanv) {
  int i = threadIdx.x;
  if (i >= 96) return;
  int b = i / 3, c = i - b * 3;
  out[(size_t)b * OUTW + 4155 + c] =
      out[(size_t)b * OUTW + 4096 + c] + cd[b * 3 + c] + meanv[b * 3 + c];
}

__global__ void size_fail_k(float* out, float code) {
  if (threadIdx.x == 0 && blockIdx.x == 0) out[0] = code;
}

// ---------------------------------------------------------------------------
extern "C" void kernel_launch(void* const* d_in, const int* in_sizes, int n_in, void* d_out,
                              int out_size, void* d_ws, size_t ws_size, hipStream_t stream) {
  float* out = (float*)d_out;
  static const int EXP[48] = {
      262144, 96, 256, 64, 4096, 64, 4096, 64, 8192, 128, 131072, 1024,
      558592, 512, 131072, 256, 32768, 128, 16384, 128, 256, 2,
      384, 128, 32768, 256, 131072, 512, 131840, 256, 32768, 128, 384, 3,
      384, 128, 16384, 128, 32768, 256, 131072, 512, 263680, 512, 131072, 256,
      15104, 59};
  if (n_in != 48) { size_fail_k<<<1, 1, 0, stream>>>(out, 9.0e6f + 99.0f * 1e4f); return; }
  if (out_size != 133056) { size_fail_k<<<1, 1, 0, stream>>>(out, 9.0e6f + 98.0f * 1e4f); return; }
  for (int i = 0; i < 48; ++i)
    if (in_sizes[i] != EXP[i]) {
      size_fail_k<<<1, 1, 0, stream>>>(out, 9.0e6f + (float)i * 1e4f);
      return;
    }
  if (ws_size < NEED_BYTES) { size_fail_k<<<1, 1, 0, stream>>>(out, 9.0e6f + 97.0f * 1e4f); return; }

  const float* pc = (const float*)d_in[0];
  const float* oh = (const float*)d_in[1];
#define IN(i) ((const float*)d_in[i])
  float* ws = (float*)d_ws;
  auto SC = [&](int s) { return ws + F_ST + (size_t)s * 2048; };
  auto SH = [&](int s) { return ws + F_ST + (size_t)s * 2048 + 1024; };
  enum { L_C1, L_C2, L_C3, L_C4, L_C5, L_S1, L_S2, L_S3, L_S4, L_T1, L_T2, L_T3,
         L_B1, L_B2, L_B3, L_B4, L_FT1, L_FT2, L_FB1, L_FB2 };

  float* Y1 = ws + F_Y1;
  float* Y2 = ws + F_Y2;
  float* Y3 = ws + F_Y3;
  float* Y4 = ws + F_Y4;
  double* P5s = (double*)(ws + F_P5S);
  double* P5q = (double*)(ws + F_P5Q);
  float*  P5m = ws + F_P5M;
  float* S1 = ws + F_S1;
  float* S2 = ws + F_S2;
  float* S3 = ws + F_S3;
  float* S4 = ws + F_S4;
  int* mask = (int*)(ws + F_MASK);
  int* midx = (int*)(ws + F_MIDX);
  int* cnt = (int*)(ws + F_CNT);
  float* meanv = ws + F_MEAN;
  float* gvec = ws + F_GVEC;
  float* gvt = ws + F_GVT;
  float* gvb = ws + F_GVB;
  float* gdot = ws + F_GDOT;
  float* obj = ws + F_OBJ;
  float* T1 = ws + F_T1;
  float* T2 = ws + F_T2;
  float* Bb1 = ws + F_B1;
  float* Bb2 = ws + F_B2;
  float* Bb3 = ws + F_B3;
  double* PTs = (double*)(ws + F_PT);
  double* PTq = (double*)(ws + F_PT + (size_t)2 * 256 * 512);
  float*  PTm = ws + F_PT + (size_t)4 * 256 * 512;
  double* PBs = (double*)(ws + F_PB);
  double* PBq = (double*)(ws + F_PB + (size_t)2 * 256 * 512);
  float*  PBm = ws + F_PB + (size_t)4 * 256 * 512;
  float* yt1 = ws + F_YT1;
  float* yt2 = ws + F_YT2;
  float* yb1 = ws + F_YB1;
  float* yb2 = ws + F_YB2;
  float* cd = ws + F_CD;
  // transient fused-stat partials (psum base; psq = psum + NT*O doubles)
  double* PAc4 = (double*)(ws + F_PA_C4);
  double* PAs1 = (double*)(ws + F_PA_S1);
  double* PAs  = (double*)(ws + F_PA_S2);
  double* PAtb = (double*)(ws + F_PA_TB);

  dim3 blk(256);
  const int NT  = PP / 128;    // 512
  const int NT2 = PP2 / 128;   // 128
  // ---- sf chain ----
  conv_pc_k<<<dim3(PP / 256, 64), blk, 0, stream>>>(pc, IN(2), IN(3), Y1);
  stats_k<<<64, blk, 0, stream>>>(Y1, PP, SC(L_C1), SH(L_C1));
  conv_gemm_k<<<dim3(1, PP / 64), blk, 0, stream>>>(Y1, PP, IN(4), 64, 64, IN(5),
      SC(L_C1), SH(L_C1), 1, Y2, PP);
  stats_k<<<64, blk, 0, stream>>>(Y2, PP, SC(L_C2), SH(L_C2));
  conv_gemm_k<<<dim3(1, PP / 64), blk, 0, stream>>>(Y2, PP, IN(6), 64, 64, IN(7),
      SC(L_C2), SH(L_C2), 1, Y3, PP);
  stats_k<<<64, blk, 0, stream>>>(Y3, PP, SC(L_C3), SH(L_C3));
  gemm_big_k<1><<<dim3(1, NT), blk, 0, stream>>>(Y3, PP, IN(8), 64, 64, IN(9),
      SC(L_C3), SH(L_C3), 1, nullptr, Y4, PP, PAc4, PAc4 + (size_t)NT * 128, nullptr, 128);
  stats_reduce_k<<<1, blk, 0, stream>>>(PAc4, PAc4 + (size_t)NT * 128, NT, 128, 1.0 / PP,
                                        SC(L_C4), SH(L_C4));
  gemm_big_k<2><<<dim3(8, NT), blk, 0, stream>>>(Y4, PP, IN(10), 128, 128, IN(11),
      SC(L_C4), SH(L_C4), 1, nullptr, nullptr, PP, P5s, P5q, P5m, 1024);
  stats_reduce_k<<<4, blk, 0, stream>>>(P5s, P5q, NT, 1024, 1.0 / PP, SC(L_C5), SH(L_C5));
  onehot_k<<<1, 96, 0, stream>>>(oh, gvec, gvt, gvb);
  maxpool_g_k<<<(32 * 1024) / 256, blk, 0, stream>>>(P5m, 16, 1024, SC(L_C5), SH(L_C5), 0,
                                                     gvec, 1027, 3);
  gdot_k<<<64, blk, 0, stream>>>(IN(12), gvec, gdot);
  // ---- seg head ----
  gemm_big_k<1><<<dim3(4, NT), blk, 0, stream>>>(Y2, PP, IN(12) + 1027, 1091, 64,
      IN(13), SC(L_C2), SH(L_C2), 1, gdot, S1, PP, PAs1, PAs1 + (size_t)NT * 512, nullptr,
      512);
  stats_reduce_k<<<2, blk, 0, stream>>>(PAs1, PAs1 + (size_t)NT * 512, NT, 512, 1.0 / PP,
                                        SC(L_S1), SH(L_S1));
  gemm_big_k<1><<<dim3(2, NT), blk, 0, stream>>>(S1, PP, IN(14), 512, 512, IN(15),
      SC(L_S1), SH(L_S1), 1, nullptr, S2, PP, PAs, PAs + (size_t)NT * 256, nullptr, 256);
  stats_reduce_k<<<1, blk, 0, stream>>>(PAs, PAs + (size_t)NT * 256, NT, 256, 1.0 / PP,
                                        SC(L_S2), SH(L_S2));
  gemm_big_k<1><<<dim3(1, NT), blk, 0, stream>>>(S2, PP, IN(16), 256, 256, IN(17),
      SC(L_S2), SH(L_S2), 1, nullptr, S3, PP, PAs, PAs + (size_t)NT * 128, nullptr, 128);
  stats_reduce_k<<<1, blk, 0, stream>>>(PAs, PAs + (size_t)NT * 128, NT, 128, 1.0 / PP,
                                        SC(L_S3), SH(L_S3));
  gemm_big_k<1><<<dim3(1, NT), blk, 0, stream>>>(S3, PP, IN(18), 128, 128, IN(19),
      SC(L_S3), SH(L_S3), 1, nullptr, S4, PP, PAs, PAs + (size_t)NT * 128, nullptr, 128);
  stats_reduce_k<<<1, blk, 0, stream>>>(PAs, PAs + (size_t)NT * 128, NT, 128, 1.0 / PP,
                                        SC(L_S4), SH(L_S4));
  logits_k<<<PP / 256, blk, 0, stream>>>(S4, IN(20), IN(21), SC(L_S4), SH(L_S4), out, mask);
  compact_k<<<32, blk, 0, stream>>>(mask, pc, midx, cnt, meanv);
  sample_k<<<64, blk, 0, stream>>>(pc, midx, cnt, meanv, obj);
  // ---- t-net ----
  conv_k3_k<<<dim3(PP2 / 256, 128), blk, 0, stream>>>(obj, IN(22), IN(23), nullptr, T1);
  stats_k<<<128, blk, 0, stream>>>(T1, PP2, SC(L_T1), SH(L_T1));
  gemm_big_k<1><<<dim3(2, NT2), blk, 0, stream>>>(T1, PP2, IN(24), 128, 128,
      IN(25), SC(L_T1), SH(L_T1), 1, nullptr, T2, PP2, PAtb, PAtb + (size_t)NT2 * 256,
      nullptr, 256);
  stats_reduce_k<<<1, blk, 0, stream>>>(PAtb, PAtb + (size_t)NT2 * 256, NT2, 256, 1.0 / PP2,
                                        SC(L_T2), SH(L_T2));
  gemm_big_k<2><<<dim3(4, NT2), blk, 0, stream>>>(T2, PP2, IN(26), 256, 256,
      IN(27), SC(L_T2), SH(L_T2), 1, nullptr, nullptr, PP2, PTs, PTq, PTm, 512);
  stats_reduce_k<<<2, blk, 0, stream>>>(PTs, PTq, NT2, 512, 1.0 / PP2, SC(L_T3), SH(L_T3));
  maxpool_g_k<<<(32 * 512) / 256, blk, 0, stream>>>(PTm, 4, 512, SC(L_T3), SH(L_T3), 1, gvt,
                                                    515, 3);
  fc_gemm_k<<<dim3(1, 32), blk, 0, stream>>>(gvt, 515, 515, IN(28), IN(29), nullptr, nullptr,
                                             0, yt1, 256, 0, 256);
  fc_stats_k<<<1, blk, 0, stream>>>(yt1, 256, 256, SC(L_FT1), SH(L_FT1));
  fc_gemm_k<<<dim3(1, 32), blk, 0, stream>>>(yt1, 256, 256, IN(30), IN(31), SC(L_FT1),
                                             SH(L_FT1), 1, yt2, 128, 0, 128);
  fc_stats_k<<<1, blk, 0, stream>>>(yt2, 128, 128, SC(L_FT2), SH(L_FT2));
  fc_gemm_k<<<dim3(1, 32), blk, 0, stream>>>(yt2, 128, 128, IN(32), IN(33), SC(L_FT2),
                                             SH(L_FT2), 1, cd, 3, 0, 3);
  // ---- box net ----
  conv_k3_k<<<dim3(PP2 / 256, 128), blk, 0, stream>>>(obj, IN(34), IN(35), cd, Bb1);
  stats_k<<<128, blk, 0, stream>>>(Bb1, PP2, SC(L_B1), SH(L_B1));
  gemm_big_k<1><<<dim3(1, NT2), blk, 0, stream>>>(Bb1, PP2, IN(36), 128, 128,
      IN(37), SC(L_B1), SH(L_B1), 1, nullptr, Bb2, PP2, PAtb, PAtb + (size_t)NT2 * 128,
      nullptr, 128);
  stats_reduce_k<<<1, blk, 0, stream>>>(PAtb, PAtb + (size_t)NT2 * 128, NT2, 128, 1.0 / PP2,
                                        SC(L_B2), SH(L_B2));
  gemm_big_k<1><<<dim3(2, NT2), blk, 0, stream>>>(Bb2, PP2, IN(38), 128, 128,
      IN(39), SC(L_B2), SH(L_B2), 1, nullptr, Bb3, PP2, PAtb, PAtb + (size_t)NT2 * 256,
      nullptr, 256);
  stats_reduce_k<<<1, blk, 0, stream>>>(PAtb, PAtb + (size_t)NT2 * 256, NT2, 256, 1.0 / PP2,
                                        SC(L_B3), SH(L_B3));
  gemm_big_k<2><<<dim3(4, NT2), blk, 0, stream>>>(Bb3, PP2, IN(40), 256, 256,
      IN(41), SC(L_B3), SH(L_B3), 1, nullptr, nullptr, PP2, PBs, PBq, PBm, 512);
  stats_reduce_k<<<2, blk, 0, stream>>>(PBs, PBq, NT2, 512, 1.0 / PP2, SC(L_B4), SH(L_B4));
  maxpool_g_k<<<(32 * 512) / 256, blk, 0, stream>>>(PBm, 4, 512, SC(L_B4), SH(L_B4), 1, gvb,
                                                    515, 0);
  fc_gemm_k<<<dim3(2, 32), blk, 0, stream>>>(gvb, 515, 515, IN(42), IN(43), nullptr, nullptr,
                                             0, yb1, 512, 0, 512);
  fc_stats_k<<<2, blk, 0, stream>>>(yb1, 512, 512, SC(L_FB1), SH(L_FB1));
  fc_gemm_k<<<dim3(1, 32), blk, 0, stream>>>(yb1, 512, 512, IN(44), IN(45), SC(L_FB1),
                                             SH(L_FB1), 1, yb2, 256, 0, 256);
  fc_stats_k<<<1, blk, 0, stream>>>(yb2, 256, 256, SC(L_FB2), SH(L_FB2));
  fc_gemm_k<<<dim3(1, 32), blk, 0, stream>>>(yb2, 256, 256, IN(46), IN(47), SC(L_FB2),
                                             SH(L_FB2), 1, out, OUTW, 4096, 59);
  center_k<<<1, 96, 0, stream>>>(out, cd, meanv);
#undef IN
}

// Round 17
// 2392.608 us; speedup vs baseline: 1.1930x; 1.1930x over previous
//
#include <hip/hip_runtime.h>
#include <cstdint>

// ---------------------------------------------------------------------------
// Frustum-PointNet forward, MI355X.  R17 = exact revert to R14 (best: 2393us).
// 128x128-tile fp32 GEMM, 8x8 acc/thread, split-halves fragment map.
// Separate stats_k dispatches (R16's fused-stats finisher serialization lost
// more than the fusion saved).  JAX partitionable threefry sampling.
// ---------------------------------------------------------------------------

constexpr int PP   = 65536;   // B*N
constexpr int PP2  = 16384;   // B*M
constexpr int OUTW = 4158;    // 2*N + 59 + 3

constexpr size_t F_Y1 = 0;
constexpr size_t F_Y2 = (size_t)64 * PP;
constexpr size_t F_Y3 = (size_t)128 * PP;
constexpr size_t F_Y4 = (size_t)192 * PP;
constexpr size_t F_P5S = 0;
constexpr size_t F_P5Q = (size_t)2 * 1024 * 1024;
constexpr size_t F_P5M = (size_t)128 * PP;
static_assert(F_P5Q + 2 * 1024 * 1024 <= F_Y2, "P5 partials exceed Y1 slot");
static_assert(F_P5M + 1024 * 1024 <= (size_t)192 * PP, "P5m exceeds Y3 slot");
constexpr size_t F_S1 = (size_t)320 * PP;
constexpr size_t F_S2 = 0;
constexpr size_t F_S3 = (size_t)320 * PP;
constexpr size_t F_S4 = (size_t)448 * PP;
constexpr size_t F_T1 = 0;
constexpr size_t F_T2 = F_T1 + (size_t)128 * PP2;
constexpr size_t F_PT = F_T2 + (size_t)256 * PP2;
constexpr size_t F_B1 = F_PT + (size_t)5 * 256 * 512;
constexpr size_t F_B2 = F_B1 + (size_t)128 * PP2;
constexpr size_t F_B3 = F_B2 + (size_t)128 * PP2;
constexpr size_t F_PB = F_B3 + (size_t)256 * PP2;
static_assert(F_PB + (size_t)5 * 256 * 512 <= (size_t)256 * PP, "t/b overlay overflow");
static_assert((F_PT % 2) == 0 && (F_PB % 2) == 0, "double alignment");

constexpr size_t SB       = (size_t)832 * PP;
constexpr size_t F_MASK   = SB;
constexpr size_t F_MIDX   = F_MASK + PP;
constexpr size_t F_CNT    = F_MIDX + PP;
constexpr size_t F_MEAN   = F_CNT + 32;
constexpr size_t F_GVEC   = F_MEAN + 96;
constexpr size_t F_GVT    = F_GVEC + 32 * 1027;
constexpr size_t F_GVB    = F_GVT + 32 * 515;
constexpr size_t F_GDOT   = F_GVB + 32 * 515;
constexpr size_t F_YT1    = F_GDOT + 512 * 32;
constexpr size_t F_YT2    = F_YT1 + 32 * 256;
constexpr size_t F_YB1    = F_YT2 + 32 * 128;
constexpr size_t F_YB2    = F_YB1 + 32 * 512;
constexpr size_t F_CD     = F_YB2 + 32 * 256;
constexpr size_t F_OBJ    = F_CD + 96;
constexpr size_t F_ST     = F_OBJ + (size_t)3 * PP2;
constexpr size_t F_END    = F_ST + 20 * 2048;
constexpr size_t NEED_BYTES = F_END * 4;           // ~219.7 MB

#define NEG_INF (-3.402823466e38f)

// ---------------------------------------------------------------------------
__global__ __launch_bounds__(256) void conv_pc_k(const float* __restrict__ pc,
                                                 const float* __restrict__ W,
                                                 const float* __restrict__ bias,
                                                 float* __restrict__ Y) {
  int p = blockIdx.x * 256 + threadIdx.x;
  int o = blockIdx.y;
  float4 v = *reinterpret_cast<const float4*>(&pc[(size_t)p * 4]);
  float s = bias[o] + v.x * W[o * 4 + 0] + v.y * W[o * 4 + 1] + v.z * W[o * 4 + 2] +
            v.w * W[o * 4 + 3];
  Y[(size_t)o * PP + p] = s;
}

__global__ __launch_bounds__(256) void conv_k3_k(const float* __restrict__ Xc,
                                                 const float* __restrict__ W,
                                                 const float* __restrict__ bias,
                                                 const float* __restrict__ cd,
                                                 float* __restrict__ Y) {
  int p = blockIdx.x * 256 + threadIdx.x;
  int o = blockIdx.y;
  int b = p >> 9;  // M=512
  float x0 = Xc[p], x1 = Xc[PP2 + p], x2 = Xc[2 * PP2 + p];
  if (cd) { x0 -= cd[b * 3]; x1 -= cd[b * 3 + 1]; x2 -= cd[b * 3 + 2]; }
  Y[(size_t)o * PP2 + p] = bias[o] + x0 * W[o * 3] + x1 * W[o * 3 + 1] + x2 * W[o * 3 + 2];
}

// ---------------------------------------------------------------------------
// 64x64-tile fp32 GEMM (O=64 layers conv2/conv3).
__global__ __launch_bounds__(256) void conv_gemm_k(
    const float* __restrict__ X, int ldx, const float* __restrict__ W, int ldw, int C,
    const float* __restrict__ bias, const float* __restrict__ scale,
    const float* __restrict__ shift, int relu_in, float* __restrict__ Y, int Ptot) {
  __shared__ float Xs[16][64];
  __shared__ float Ws[64][17];
  const int tid = threadIdx.x;
  const int tx = tid & 15, ty = tid >> 4;
  const int o0 = blockIdx.x * 64, p0 = blockIdx.y * 64;
  float acc[4][4] = {};
  for (int c0 = 0; c0 < C; c0 += 16) {
#pragma unroll
    for (int j = 0; j < 4; ++j) {
      int idx = tid + j * 256;
      int k = idx >> 6, n = idx & 63;
      int c = c0 + k;
      float v = X[(size_t)c * ldx + p0 + n];
      if (scale) v = v * scale[c] + shift[c];
      if (relu_in) v = fmaxf(v, 0.f);
      Xs[k][n] = v;
    }
#pragma unroll
    for (int j = 0; j < 4; ++j) {
      int idx = tid + j * 256;
      int o = idx >> 4, k = idx & 15;
      Ws[o][k] = W[(size_t)(o0 + o) * ldw + c0 + k];
    }
    __syncthreads();
#pragma unroll
    for (int k = 0; k < 16; ++k) {
      float bx[4], aw[4];
#pragma unroll
      for (int j = 0; j < 4; ++j) bx[j] = Xs[k][tx * 4 + j];
#pragma unroll
      for (int i = 0; i < 4; ++i) aw[i] = Ws[ty * 4 + i][k];
#pragma unroll
      for (int i = 0; i < 4; ++i)
#pragma unroll
        for (int j = 0; j < 4; ++j) acc[i][j] = fmaf(aw[i], bx[j], acc[i][j]);
    }
    __syncthreads();
  }
#pragma unroll
  for (int i = 0; i < 4; ++i) {
    int o = o0 + ty * 4 + i;
    float badd = bias[o];
#pragma unroll
    for (int j = 0; j < 4; ++j) acc[i][j] += badd;
  }
#pragma unroll
  for (int i = 0; i < 4; ++i) {
    int o = o0 + ty * 4 + i;
    float4 v = make_float4(acc[i][0], acc[i][1], acc[i][2], acc[i][3]);
    *reinterpret_cast<float4*>(&Y[(size_t)o * Ptot + p0 + tx * 4]) = v;
  }
}

// ---------------------------------------------------------------------------
// 128x128-tile fp32 GEMM, 8x8 acc/thread, split-halves fragment map.
template <bool FUSED>
__global__ __launch_bounds__(256) void gemm_big_k(
    const float* __restrict__ X, int ldx, const float* __restrict__ W, int ldw, int C,
    const float* __restrict__ bias, const float* __restrict__ scale,
    const float* __restrict__ shift, int relu_in, const float* __restrict__ gadd,
    float* __restrict__ Y, int Ptot, double* __restrict__ psum, double* __restrict__ psq,
    float* __restrict__ pmax, int Ototal) {
  __shared__ float Xs[16][128];
  __shared__ float Wt[16][128];
  const int tid = threadIdx.x;
  const int tx = tid & 15, ty = tid >> 4;
  const int o0 = blockIdx.x * 128, p0 = blockIdx.y * 128;
  float acc[8][8] = {};
  for (int c0 = 0; c0 < C; c0 += 16) {
#pragma unroll
    for (int q = 0; q < 2; ++q) {
      int f = tid + q * 256;
      int k = f >> 5, c4 = f & 31;
      int c = c0 + k;
      float4 v = *reinterpret_cast<const float4*>(&X[(size_t)c * ldx + p0 + c4 * 4]);
      if (scale) {
        float sc = scale[c], sh = shift[c];
        v.x = v.x * sc + sh; v.y = v.y * sc + sh;
        v.z = v.z * sc + sh; v.w = v.w * sc + sh;
      }
      if (relu_in) {
        v.x = fmaxf(v.x, 0.f); v.y = fmaxf(v.y, 0.f);
        v.z = fmaxf(v.z, 0.f); v.w = fmaxf(v.w, 0.f);
      }
      *reinterpret_cast<float4*>(&Xs[k][c4 * 4]) = v;
    }
#pragma unroll
    for (int q = 0; q < 8; ++q) {
      int idx = tid + q * 256;
      int k = idx >> 7, o = idx & 127;
      Wt[k][o] = W[(size_t)(o0 + o) * ldw + c0 + k];
    }
    __syncthreads();
#pragma unroll
    for (int k = 0; k < 16; ++k) {
      float bx[8], aw[8];
      *reinterpret_cast<float4*>(&bx[0]) =
          *reinterpret_cast<const float4*>(&Xs[k][tx * 4]);
      *reinterpret_cast<float4*>(&bx[4]) =
          *reinterpret_cast<const float4*>(&Xs[k][64 + tx * 4]);
      *reinterpret_cast<float4*>(&aw[0]) =
          *reinterpret_cast<const float4*>(&Wt[k][ty * 4]);
      *reinterpret_cast<float4*>(&aw[4]) =
          *reinterpret_cast<const float4*>(&Wt[k][64 + ty * 4]);
#pragma unroll
      for (int i = 0; i < 8; ++i)
#pragma unroll
        for (int j = 0; j < 8; ++j) acc[i][j] = fmaf(aw[i], bx[j], acc[i][j]);
    }
    __syncthreads();
  }
#pragma unroll
  for (int i = 0; i < 8; ++i) {
    int ro = (i < 4) ? (ty * 4 + i) : (64 + ty * 4 + (i - 4));
    int o = o0 + ro;
    float badd = bias ? bias[o] : 0.f;
    if (gadd) badd += gadd[o * 32 + (p0 >> 11)];
#pragma unroll
    for (int j = 0; j < 8; ++j) acc[i][j] += badd;
  }
  if constexpr (!FUSED) {
#pragma unroll
    for (int i = 0; i < 8; ++i) {
      int ro = (i < 4) ? (ty * 4 + i) : (64 + ty * 4 + (i - 4));
      float* row = &Y[(size_t)(o0 + ro) * Ptot + p0];
      *reinterpret_cast<float4*>(row + tx * 4) =
          make_float4(acc[i][0], acc[i][1], acc[i][2], acc[i][3]);
      *reinterpret_cast<float4*>(row + 64 + tx * 4) =
          make_float4(acc[i][4], acc[i][5], acc[i][6], acc[i][7]);
    }
  } else {
    __shared__ double redd[16][128];
#pragma unroll
    for (int i = 0; i < 8; ++i) {
      int ro = (i < 4) ? (ty * 4 + i) : (64 + ty * 4 + (i - 4));
      double s = 0.0;
#pragma unroll
      for (int j = 0; j < 8; ++j) s += (double)acc[i][j];
      redd[tx][ro] = s;
    }
    __syncthreads();
    if (tid < 128) {
      double s = 0.0;
      for (int t = 0; t < 16; ++t) s += redd[t][tid];
      psum[(size_t)blockIdx.y * Ototal + o0 + tid] = s;
    }
    __syncthreads();
#pragma unroll
    for (int i = 0; i < 8; ++i) {
      int ro = (i < 4) ? (ty * 4 + i) : (64 + ty * 4 + (i - 4));
      double s = 0.0;
#pragma unroll
      for (int j = 0; j < 8; ++j) s += (double)acc[i][j] * (double)acc[i][j];
      redd[tx][ro] = s;
    }
    __syncthreads();
    if (tid < 128) {
      double s = 0.0;
      for (int t = 0; t < 16; ++t) s += redd[t][tid];
      psq[(size_t)blockIdx.y * Ototal + o0 + tid] = s;
    }
    __syncthreads();
#pragma unroll
    for (int i = 0; i < 8; ++i) {
      int ro = (i < 4) ? (ty * 4 + i) : (64 + ty * 4 + (i - 4));
      float mx = acc[i][0];
#pragma unroll
      for (int j = 1; j < 8; ++j) mx = fmaxf(mx, acc[i][j]);
      redd[tx][ro] = (double)mx;
    }
    __syncthreads();
    if (tid < 128) {
      double s = -1.0e300;
      for (int t = 0; t < 16; ++t) s = s > redd[t][tid] ? s : redd[t][tid];
      pmax[(size_t)blockIdx.y * Ototal + o0 + tid] = (float)s;
    }
  }
}

// BN stats over stored (O x Ptot) fp32 activation; fp64 accumulation.
__global__ __launch_bounds__(256) void stats_k(const float* __restrict__ Y, int Ptot,
                                               float* __restrict__ scale,
                                               float* __restrict__ shift) {
  int o = blockIdx.x;
  const float* row = Y + (size_t)o * Ptot;
  double s = 0.0, q = 0.0;
  for (int p = threadIdx.x; p < Ptot; p += 256) {
    double v = (double)row[p];
    s += v;
    q += v * v;
  }
  __shared__ double ss[256], qq[256];
  int tid = threadIdx.x;
  ss[tid] = s; qq[tid] = q;
  __syncthreads();
  for (int off = 128; off; off >>= 1) {
    if (tid < off) { ss[tid] += ss[tid + off]; qq[tid] += qq[tid + off]; }
    __syncthreads();
  }
  if (tid == 0) {
    double m = ss[0] / (double)Ptot;
    double v = qq[0] / (double)Ptot - m * m;
    if (v < 0.0) v = 0.0;
    double sc = 1.0 / sqrt(v + 1e-5);
    scale[o] = (float)sc;
    shift[o] = (float)(-m * sc);
  }
}

__global__ void stats_reduce_k(const double* __restrict__ psum, const double* __restrict__ psq,
                               int ntiles, int O, double invP, float* __restrict__ scale,
                               float* __restrict__ shift) {
  int o = blockIdx.x * blockDim.x + threadIdx.x;
  if (o >= O) return;
  double s = 0.0, q = 0.0;
  for (int t = 0; t < ntiles; ++t) {
    s += psum[(size_t)t * O + o];
    q += psq[(size_t)t * O + o];
  }
  double m = s * invP;
  double v = q * invP - m * m;
  if (v < 0.0) v = 0.0;
  double sc = 1.0 / sqrt(v + 1e-5);
  scale[o] = (float)sc;
  shift[o] = (float)(-m * sc);
}

__global__ void maxpool_g_k(const float* __restrict__ pmax, int tilesPB, int O,
                            const float* __restrict__ scale, const float* __restrict__ shift,
                            int relu, float* __restrict__ out, int ostride, int ooff) {
  int idx = blockIdx.x * blockDim.x + threadIdx.x;
  if (idx >= 32 * O) return;
  int b = idx / O, o = idx - b * O;
  float m = NEG_INF;
  for (int t = b * tilesPB; t < (b + 1) * tilesPB; ++t) m = fmaxf(m, pmax[(size_t)t * O + o]);
  float v = scale[o] * m + shift[o];
  if (relu) v = fmaxf(v, 0.f);
  out[(size_t)b * ostride + ooff + o] = v;
}

__global__ void onehot_k(const float* __restrict__ oh, float* __restrict__ gvec,
                         float* __restrict__ gvt, float* __restrict__ gvb) {
  int i = threadIdx.x;
  if (i >= 96) return;
  int b = i / 3, c = i - b * 3;
  float v = oh[b * 3 + c];
  gvec[b * 1027 + c] = v;
  gvt[b * 515 + c] = v;
  gvb[b * 515 + 512 + c] = v;
}

__global__ void gdot_k(const float* __restrict__ W, const float* __restrict__ gvec,
                       float* __restrict__ gdot) {
  int idx = blockIdx.x * 256 + threadIdx.x;  // 512*32
  int o = idx >> 5, b = idx & 31;
  double s = 0.0;
  const float* wr = W + (size_t)o * 1091;
  const float* gr = gvec + (size_t)b * 1027;
  for (int c = 0; c < 1027; ++c) s += (double)wr[c] * (double)gr[c];
  gdot[o * 32 + b] = (float)s;
}

__global__ __launch_bounds__(256) void logits_k(const float* __restrict__ S4,
                                                const float* __restrict__ W,
                                                const float* __restrict__ bias,
                                                const float* __restrict__ scale,
                                                const float* __restrict__ shift,
                                                float* __restrict__ out,
                                                int* __restrict__ mask) {
  int p = blockIdx.x * 256 + threadIdx.x;
  double l0 = (double)bias[0], l1 = (double)bias[1];
  for (int c = 0; c < 128; ++c) {
    float v = fmaxf(S4[(size_t)c * PP + p] * scale[c] + shift[c], 0.f);
    l0 += (double)v * (double)W[c];
    l1 += (double)v * (double)W[128 + c];
  }
  int b = p >> 11, n = p & 2047;
  out[(size_t)b * OUTW + 2 * n] = (float)l0;
  out[(size_t)b * OUTW + 2 * n + 1] = (float)l1;
  mask[p] = (l0 < l1) ? 1 : 0;
}

__global__ __launch_bounds__(256) void compact_k(const int* __restrict__ mask,
                                                 const float* __restrict__ pc,
                                                 int* __restrict__ midx, int* __restrict__ cnt,
                                                 float* __restrict__ meanv) {
  int b = blockIdx.x, tid = threadIdx.x;
  __shared__ int sc[256];
  __shared__ int base;
  __shared__ double red[256];
  __shared__ double totals[3];
  if (tid == 0) base = 0;
  __syncthreads();
  double sx = 0.0, sy = 0.0, sz = 0.0;
  for (int n0 = 0; n0 < 2048; n0 += 256) {
    int n = n0 + tid;
    int mval = mask[b * 2048 + n];
    sc[tid] = mval;
    __syncthreads();
    for (int off = 1; off < 256; off <<= 1) {
      int v = (tid >= off) ? sc[tid - off] : 0;
      __syncthreads();
      sc[tid] += v;
      __syncthreads();
    }
    int excl = sc[tid] - mval;
    if (mval) {
      midx[b * 2048 + base + excl] = n;
      const float* q = &pc[((size_t)(b * 2048 + n)) * 4];
      sx += (double)q[0]; sy += (double)q[1]; sz += (double)q[2];
    }
    __syncthreads();
    if (tid == 0) base += sc[255];
    __syncthreads();
  }
  red[tid] = sx; __syncthreads();
  for (int off = 128; off; off >>= 1) { if (tid < off) red[tid] += red[tid + off]; __syncthreads(); }
  if (tid == 0) totals[0] = red[0];
  __syncthreads();
  red[tid] = sy; __syncthreads();
  for (int off = 128; off; off >>= 1) { if (tid < off) red[tid] += red[tid + off]; __syncthreads(); }
  if (tid == 0) totals[1] = red[0];
  __syncthreads();
  red[tid] = sz; __syncthreads();
  for (int off = 128; off; off >>= 1) { if (tid < off) red[tid] += red[tid + off]; __syncthreads(); }
  if (tid == 0) {
    totals[2] = red[0];
    int c = base;
    cnt[b] = c;
    double d = (double)(c > 1 ? c : 1);
    meanv[b * 3 + 0] = (float)(totals[0] / d);
    meanv[b * 3 + 1] = (float)(totals[1] / d);
    meanv[b * 3 + 2] = (float)(totals[2] / d);
  }
}

// --------------------------- threefry2x32 ----------------------------------
__device__ __forceinline__ uint32_t rotl32(uint32_t x, int r) {
  return (x << r) | (x >> (32 - r));
}
__device__ inline void threefry2x32(uint32_t k0, uint32_t k1, uint32_t& x0, uint32_t& x1) {
  const uint32_t ks[3] = {k0, k1, k0 ^ k1 ^ 0x1BD11BDAu};
  const int rot[2][4] = {{13, 15, 26, 6}, {17, 29, 16, 24}};
  x0 += ks[0]; x1 += ks[1];
  for (int i = 0; i < 5; ++i) {
    const int* r = rot[i & 1];
    for (int j = 0; j < 4; ++j) {
      x0 += x1; x1 = rotl32(x1, r[j]); x1 ^= x0;
    }
    x0 += ks[(i + 1) % 3];
    x1 += ks[(i + 2) % 3] + (uint32_t)(i + 1);
  }
}

// JAX partitionable threefry (default since 0.4.36): ctr (0,e), bits = w0^w1.
__global__ void sample_k(const float* __restrict__ pc, const int* __restrict__ midx,
                         const int* __restrict__ cnt, const float* __restrict__ meanv,
                         float* __restrict__ obj) {
  int e = blockIdx.x * 256 + threadIdx.x;
  if (e >= 16384) return;
  uint32_t x0 = 0u, x1 = (uint32_t)e;
  threefry2x32(0u, 42u, x0, x1);
  uint32_t bits = x0 ^ x1;
  float u = __uint_as_float((bits >> 9) | 0x3F800000u) - 1.0f;
  int b = e >> 9;
  int m = e & 511;
  int c_ = cnt[b];
  int pos = (int)(u * (float)c_);
  int cap = c_ - 1; if (cap < 0) cap = 0;
  if (pos > cap) pos = cap;
  float vx = 0.f, vy = 0.f, vz = 0.f;
  if (c_ > 0) {
    int n = midx[b * 2048 + pos];
    const float* q = &pc[((size_t)(b * 2048 + n)) * 4];
    vx = q[0] - meanv[b * 3 + 0];
    vy = q[1] - meanv[b * 3 + 1];
    vz = q[2] - meanv[b * 3 + 2];
  }
  int p2 = b * 512 + m;
  obj[p2] = vx;
  obj[PP2 + p2] = vy;
  obj[2 * PP2 + p2] = vz;
}

__global__ void fc_gemm_k(const float* __restrict__ Xf, int ldx, int K,
                          const float* __restrict__ W, const float* __restrict__ bias,
                          const float* __restrict__ scale, const float* __restrict__ shift,
                          int relu, float* __restrict__ Y, int ldy, int yoff, int O) {
  int o = blockIdx.x * blockDim.x + threadIdx.x;
  int b = blockIdx.y;
  if (o >= O) return;
  const float* x = Xf + (size_t)b * ldx;
  const float* w = W + (size_t)o * K;
  double s = bias ? (double)bias[o] : 0.0;
  for (int k = 0; k < K; ++k) {
    float v = x[k];
    if (scale) {
      v = v * scale[k] + shift[k];
      if (relu) v = fmaxf(v, 0.f);
    }
    s += (double)v * (double)w[k];
  }
  Y[(size_t)b * ldy + yoff + o] = (float)s;
}

__global__ void fc_stats_k(const float* __restrict__ Y, int ldy, int O,
                           float* __restrict__ scale, float* __restrict__ shift) {
  int o = blockIdx.x * blockDim.x + threadIdx.x;
  if (o >= O) return;
  double s = 0.0, q = 0.0;
  for (int b = 0; b < 32; ++b) {
    double v = (double)Y[(size_t)b * ldy + o];
    s += v;
    q += v * v;
  }
  double m = s / 32.0;
  double v = q / 32.0 - m * m;
  if (v < 0.0) v = 0.0;
  double sc = 1.0 / sqrt(v + 1e-5);
  scale[o] = (float)sc;
  shift[o] = (float)(-m * sc);
}

__global__ void center_k(float* __restrict__ out, const float* __restrict__ cd,
                         const float* __restrict__ meanv) {
  int i = threadIdx.x;
  if (i >= 96) return;
  int b = i / 3, c = i - b * 3;
  out[(size_t)b * OUTW + 4155 + c] =
      out[(size_t)b * OUTW + 4096 + c] + cd[b * 3 + c] + meanv[b * 3 + c];
}

__global__ void size_fail_k(float* out, float code) {
  if (threadIdx.x == 0 && blockIdx.x == 0) out[0] = code;
}

// ---------------------------------------------------------------------------
extern "C" void kernel_launch(void* const* d_in, const int* in_sizes, int n_in, void* d_out,
                              int out_size, void* d_ws, size_t ws_size, hipStream_t stream) {
  float* out = (float*)d_out;
  static const int EXP[48] = {
      262144, 96, 256, 64, 4096, 64, 4096, 64, 8192, 128, 131072, 1024,
      558592, 512, 131072, 256, 32768, 128, 16384, 128, 256, 2,
      384, 128, 32768, 256, 131072, 512, 131840, 256, 32768, 128, 384, 3,
      384, 128, 16384, 128, 32768, 256, 131072, 512, 263680, 512, 131072, 256,
      15104, 59};
  if (n_in != 48) { size_fail_k<<<1, 1, 0, stream>>>(out, 9.0e6f + 99.0f * 1e4f); return; }
  if (out_size != 133056) { size_fail_k<<<1, 1, 0, stream>>>(out, 9.0e6f + 98.0f * 1e4f); return; }
  for (int i = 0; i < 48; ++i)
    if (in_sizes[i] != EXP[i]) {
      size_fail_k<<<1, 1, 0, stream>>>(out, 9.0e6f + (float)i * 1e4f);
      return;
    }
  if (ws_size < NEED_BYTES) { size_fail_k<<<1, 1, 0, stream>>>(out, 9.0e6f + 97.0f * 1e4f); return; }

  const float* pc = (const float*)d_in[0];
  const float* oh = (const float*)d_in[1];
#define IN(i) ((const float*)d_in[i])
  float* ws = (float*)d_ws;
  auto SC = [&](int s) { return ws + F_ST + (size_t)s * 2048; };
  auto SH = [&](int s) { return ws + F_ST + (size_t)s * 2048 + 1024; };
  enum { L_C1, L_C2, L_C3, L_C4, L_C5, L_S1, L_S2, L_S3, L_S4, L_T1, L_T2, L_T3,
         L_B1, L_B2, L_B3, L_B4, L_FT1, L_FT2, L_FB1, L_FB2 };

  float* Y1 = ws + F_Y1;
  float* Y2 = ws + F_Y2;
  float* Y3 = ws + F_Y3;
  float* Y4 = ws + F_Y4;
  double* P5s = (double*)(ws + F_P5S);
  double* P5q = (double*)(ws + F_P5Q);
  float*  P5m = ws + F_P5M;
  float* S1 = ws + F_S1;
  float* S2 = ws + F_S2;
  float* S3 = ws + F_S3;
  float* S4 = ws + F_S4;
  int* mask = (int*)(ws + F_MASK);
  int* midx = (int*)(ws + F_MIDX);
  int* cnt = (int*)(ws + F_CNT);
  float* meanv = ws + F_MEAN;
  float* gvec = ws + F_GVEC;
  float* gvt = ws + F_GVT;
  float* gvb = ws + F_GVB;
  float* gdot = ws + F_GDOT;
  float* obj = ws + F_OBJ;
  float* T1 = ws + F_T1;
  float* T2 = ws + F_T2;
  float* Bb1 = ws + F_B1;
  float* Bb2 = ws + F_B2;
  float* Bb3 = ws + F_B3;
  double* PTs = (double*)(ws + F_PT);
  double* PTq = (double*)(ws + F_PT + (size_t)2 * 256 * 512);
  float*  PTm = ws + F_PT + (size_t)4 * 256 * 512;
  double* PBs = (double*)(ws + F_PB);
  double* PBq = (double*)(ws + F_PB + (size_t)2 * 256 * 512);
  float*  PBm = ws + F_PB + (size_t)4 * 256 * 512;
  float* yt1 = ws + F_YT1;
  float* yt2 = ws + F_YT2;
  float* yb1 = ws + F_YB1;
  float* yb2 = ws + F_YB2;
  float* cd = ws + F_CD;

  dim3 blk(256);
  // ---- sf chain ----
  conv_pc_k<<<dim3(PP / 256, 64), blk, 0, stream>>>(pc, IN(2), IN(3), Y1);
  stats_k<<<64, blk, 0, stream>>>(Y1, PP, SC(L_C1), SH(L_C1));
  conv_gemm_k<<<dim3(1, PP / 64), blk, 0, stream>>>(Y1, PP, IN(4), 64, 64, IN(5),
      SC(L_C1), SH(L_C1), 1, Y2, PP);
  stats_k<<<64, blk, 0, stream>>>(Y2, PP, SC(L_C2), SH(L_C2));
  conv_gemm_k<<<dim3(1, PP / 64), blk, 0, stream>>>(Y2, PP, IN(6), 64, 64, IN(7),
      SC(L_C2), SH(L_C2), 1, Y3, PP);
  stats_k<<<64, blk, 0, stream>>>(Y3, PP, SC(L_C3), SH(L_C3));
  gemm_big_k<false><<<dim3(1, PP / 128), blk, 0, stream>>>(Y3, PP, IN(8), 64, 64, IN(9),
      SC(L_C3), SH(L_C3), 1, nullptr, Y4, PP, nullptr, nullptr, nullptr, 0);
  stats_k<<<128, blk, 0, stream>>>(Y4, PP, SC(L_C4), SH(L_C4));
  gemm_big_k<true><<<dim3(8, PP / 128), blk, 0, stream>>>(Y4, PP, IN(10), 128, 128, IN(11),
      SC(L_C4), SH(L_C4), 1, nullptr, nullptr, PP, P5s, P5q, P5m, 1024);
  stats_reduce_k<<<4, blk, 0, stream>>>(P5s, P5q, PP / 128, 1024, 1.0 / PP, SC(L_C5),
                                        SH(L_C5));
  onehot_k<<<1, 96, 0, stream>>>(oh, gvec, gvt, gvb);
  maxpool_g_k<<<(32 * 1024) / 256, blk, 0, stream>>>(P5m, 16, 1024, SC(L_C5), SH(L_C5), 0,
                                                     gvec, 1027, 3);
  gdot_k<<<64, blk, 0, stream>>>(IN(12), gvec, gdot);
  // ---- seg head ----
  gemm_big_k<false><<<dim3(4, PP / 128), blk, 0, stream>>>(Y2, PP, IN(12) + 1027, 1091, 64,
      IN(13), SC(L_C2), SH(L_C2), 1, gdot, S1, PP, nullptr, nullptr, nullptr, 0);
  stats_k<<<512, blk, 0, stream>>>(S1, PP, SC(L_S1), SH(L_S1));
  gemm_big_k<false><<<dim3(2, PP / 128), blk, 0, stream>>>(S1, PP, IN(14), 512, 512, IN(15),
      SC(L_S1), SH(L_S1), 1, nullptr, S2, PP, nullptr, nullptr, nullptr, 0);
  stats_k<<<256, blk, 0, stream>>>(S2, PP, SC(L_S2), SH(L_S2));
  gemm_big_k<false><<<dim3(1, PP / 128), blk, 0, stream>>>(S2, PP, IN(16), 256, 256, IN(17),
      SC(L_S2), SH(L_S2), 1, nullptr, S3, PP, nullptr, nullptr, nullptr, 0);
  stats_k<<<128, blk, 0, stream>>>(S3, PP, SC(L_S3), SH(L_S3));
  gemm_big_k<false><<<dim3(1, PP / 128), blk, 0, stream>>>(S3, PP, IN(18), 128, 128, IN(19),
      SC(L_S3), SH(L_S3), 1, nullptr, S4, PP, nullptr, nullptr, nullptr, 0);
  stats_k<<<128, blk, 0, stream>>>(S4, PP, SC(L_S4), SH(L_S4));
  logits_k<<<PP / 256, blk, 0, stream>>>(S4, IN(20), IN(21), SC(L_S4), SH(L_S4), out, mask);
  compact_k<<<32, blk, 0, stream>>>(mask, pc, midx, cnt, meanv);
  sample_k<<<64, blk, 0, stream>>>(pc, midx, cnt, meanv, obj);
  // ---- t-net ----
  conv_k3_k<<<dim3(PP2 / 256, 128), blk, 0, stream>>>(obj, IN(22), IN(23), nullptr, T1);
  stats_k<<<128, blk, 0, stream>>>(T1, PP2, SC(L_T1), SH(L_T1));
  gemm_big_k<false><<<dim3(2, PP2 / 128), blk, 0, stream>>>(T1, PP2, IN(24), 128, 128,
      IN(25), SC(L_T1), SH(L_T1), 1, nullptr, T2, PP2, nullptr, nullptr, nullptr, 0);
  stats_k<<<256, blk, 0, stream>>>(T2, PP2, SC(L_T2), SH(L_T2));
  gemm_big_k<true><<<dim3(4, PP2 / 128), blk, 0, stream>>>(T2, PP2, IN(26), 256, 256,
      IN(27), SC(L_T2), SH(L_T2), 1, nullptr, nullptr, PP2, PTs, PTq, PTm, 512);
  stats_reduce_k<<<2, blk, 0, stream>>>(PTs, PTq, PP2 / 128, 512, 1.0 / PP2, SC(L_T3),
                                        SH(L_T3));
  maxpool_g_k<<<(32 * 512) / 256, blk, 0, stream>>>(PTm, 4, 512, SC(L_T3), SH(L_T3), 1, gvt,
                                                    515, 3);
  fc_gemm_k<<<dim3(1, 32), blk, 0, stream>>>(gvt, 515, 515, IN(28), IN(29), nullptr, nullptr,
                                             0, yt1, 256, 0, 256);
  fc_stats_k<<<1, blk, 0, stream>>>(yt1, 256, 256, SC(L_FT1), SH(L_FT1));
  fc_gemm_k<<<dim3(1, 32), blk, 0, stream>>>(yt1, 256, 256, IN(30), IN(31), SC(L_FT1),
                                             SH(L_FT1), 1, yt2, 128, 0, 128);
  fc_stats_k<<<1, blk, 0, stream>>>(yt2, 128, 128, SC(L_FT2), SH(L_FT2));
  fc_gemm_k<<<dim3(1, 32), blk, 0, stream>>>(yt2, 128, 128, IN(32), IN(33), SC(L_FT2),
                                             SH(L_FT2), 1, cd, 3, 0, 3);
  // ---- box net ----
  conv_k3_k<<<dim3(PP2 / 256, 128), blk, 0, stream>>>(obj, IN(34), IN(35), cd, Bb1);
  stats_k<<<128, blk, 0, stream>>>(Bb1, PP2, SC(L_B1), SH(L_B1));
  gemm_big_k<false><<<dim3(1, PP2 / 128), blk, 0, stream>>>(Bb1, PP2, IN(36), 128, 128,
      IN(37), SC(L_B1), SH(L_B1), 1, nullptr, Bb2, PP2, nullptr, nullptr, nullptr, 0);
  stats_k<<<128, blk, 0, stream>>>(Bb2, PP2, SC(L_B2), SH(L_B2));
  gemm_big_k<false><<<dim3(2, PP2 / 128), blk, 0, stream>>>(Bb2, PP2, IN(38), 128, 128,
      IN(39), SC(L_B2), SH(L_B2), 1, nullptr, Bb3, PP2, nullptr, nullptr, nullptr, 0);
  stats_k<<<256, blk, 0, stream>>>(Bb3, PP2, SC(L_B3), SH(L_B3));
  gemm_big_k<true><<<dim3(4, PP2 / 128), blk, 0, stream>>>(Bb3, PP2, IN(40), 256, 256,
      IN(41), SC(L_B3), SH(L_B3), 1, nullptr, nullptr, PP2, PBs, PBq, PBm, 512);
  stats_reduce_k<<<2, blk, 0, stream>>>(PBs, PBq, PP2 / 128, 512, 1.0 / PP2, SC(L_B4),
                                        SH(L_B4));
  maxpool_g_k<<<(32 * 512) / 256, blk, 0, stream>>>(PBm, 4, 512, SC(L_B4), SH(L_B4), 1, gvb,
                                                    515, 0);
  fc_gemm_k<<<dim3(2, 32), blk, 0, stream>>>(gvb, 515, 515, IN(42), IN(43), nullptr, nullptr,
                                             0, yb1, 512, 0, 512);
  fc_stats_k<<<2, blk, 0, stream>>>(yb1, 512, 512, SC(L_FB1), SH(L_FB1));
  fc_gemm_k<<<dim3(1, 32), blk, 0, stream>>>(yb1, 512, 512, IN(44), IN(45), SC(L_FB1),
                                             SH(L_FB1), 1, yb2, 256, 0, 256);
  fc_stats_k<<<1, blk, 0, stream>>>(yb2, 256, 256, SC(L_FB2), SH(L_FB2));
  fc_gemm_k<<<dim3(1, 32), blk, 0, stream>>>(yb2, 256, 256, IN(46), IN(47), SC(L_FB2),
                                             SH(L_FB2), 1, out, OUTW, 4096, 59);
  center_k<<<1, 96, 0, stream>>>(out, cd, meanv);
#undef IN
}